// Round 1
// baseline (1398.465 us; speedup 1.0000x reference)
//
#include <hip/hip_runtime.h>

typedef __bf16 v8bf __attribute__((ext_vector_type(8)));
typedef __bf16 v2bf __attribute__((ext_vector_type(2)));
typedef float  v4f  __attribute__((ext_vector_type(4)));

// ---- problem constants (from reference) ----
static constexpr int cN1 = 200000, cN2 = 100000, cN3 = 50000;
static constexpr int cE0 = 3200000, cE1 = 1600000, cE2 = 800000;
static constexpr int F_IN = 128, F_HID = 256;

// ---------------- W convert: fp32 [K,N] -> bf16 transposed [N,K] ----------------
__global__ void wconv_kernel(const float* __restrict__ W, int K, int N,
                             __bf16* __restrict__ Wt) {
    int i = blockIdx.x * blockDim.x + threadIdx.x;
    if (i >= K * N) return;
    int k = i / N, n = i - k * N;
    Wt[(size_t)n * K + k] = (__bf16)W[i];
}

// ---------------- CSR build ----------------
__global__ void count_kernel(const int* __restrict__ rows, const int* __restrict__ cols,
                             int E, int n_dst, int* __restrict__ deg, int* __restrict__ cnt) {
    int e = blockIdx.x * blockDim.x + threadIdx.x;
    if (e >= E) return;
    int c = cols[e];
    atomicAdd(&deg[c], 1);              // degree counts ALL edges (reference semantics)
    if (rows[e] < n_dst) atomicAdd(&cnt[c], 1);  // only these contribute (dis[row]=0 otherwise)
}

__global__ void offsets_kernel(const int* __restrict__ deg, const int* __restrict__ cnt,
                               int n_dst, float fill, float* __restrict__ dis,
                               int* __restrict__ off, int* __restrict__ cur,
                               int* __restrict__ cursor) {
    int c = blockIdx.x * blockDim.x + threadIdx.x;
    if (c >= n_dst) return;
    dis[c] = rsqrtf((float)deg[c] + fill);   // deg+fill >= 1 always for c < n_dst
    int o = atomicAdd(cursor, cnt[c]);       // CSR segment order irrelevant for a sum
    off[c] = o;
    cur[c] = o;
}

__global__ void scatter_kernel(const int* __restrict__ rows, const int* __restrict__ cols,
                               int E, int n_dst, int* __restrict__ cur, int* __restrict__ csr) {
    int e = blockIdx.x * blockDim.x + threadIdx.x;
    if (e >= E) return;
    int r = rows[e];
    if (r < n_dst) {
        int p = atomicAdd(&cur[cols[e]], 1);
        csr[p] = r;
    }
}

// ---------------- aggregation: fp32 source (layer 0, F=128) ----------------
// block = 128 threads, one block per target c. agg[c] = fill*dis[c]^2*src[c]
//                                              + sum_e dis[row]*dis[c]*src[row]
__global__ void agg_f32_kernel(const float* __restrict__ src, const float* __restrict__ dis,
                               const int* __restrict__ off, const int* __restrict__ cnt,
                               const int* __restrict__ csr, float fill,
                               __bf16* __restrict__ out) {
    int c = blockIdx.x;
    int t = threadIdx.x;                 // feature index, F=128
    float dc = dis[c];
    float acc = fill * dc * dc * src[(size_t)c * F_IN + t];
    int o = off[c], n = cnt[c];
    for (int i = 0; i < n; i++) {
        int r = csr[o + i];              // broadcast load (same addr across wave)
        float coef = dis[r] * dc;
        acc += coef * src[(size_t)r * F_IN + t];
    }
    out[(size_t)c * F_IN + t] = (__bf16)acc;
}

// ---------------- aggregation: bf16 source (layers 1/2, F=256, 2 feats/thread) ----------------
__global__ void agg_bf16_kernel(const __bf16* __restrict__ src, const float* __restrict__ dis,
                                const int* __restrict__ off, const int* __restrict__ cnt,
                                const int* __restrict__ csr, float fill,
                                __bf16* __restrict__ out) {
    int c = blockIdx.x;
    int t = threadIdx.x;                 // 0..127, handles features 2t, 2t+1
    float dc = dis[c];
    float self = fill * dc * dc;
    v2bf v = *(const v2bf*)(src + (size_t)c * F_HID + 2 * t);
    float a0 = self * (float)v.x;
    float a1 = self * (float)v.y;
    int o = off[c], n = cnt[c];
    for (int i = 0; i < n; i++) {
        int r = csr[o + i];
        float coef = dis[r] * dc;
        v2bf w = *(const v2bf*)(src + (size_t)r * F_HID + 2 * t);
        a0 += coef * (float)w.x;
        a1 += coef * (float)w.y;
    }
    v2bf res;
    res.x = (__bf16)a0;
    res.y = (__bf16)a1;
    *(v2bf*)(out + (size_t)c * F_HID + 2 * t) = res;
}

// ---------------- GEMM: C[M,N] = A[M,K] @ B[K,N] + bias (opt ReLU) ----------------
// A bf16 row-major [M,K]; Bt bf16 = B transposed, row-major [N,K]. 64x64 tile,
// 4 waves each 32x32 via mfma_f32_16x16x32_bf16.
// Verified gfx950 layouts: A-frag lane l: A[m=l&15][k=(l>>4)*8+j];
// B-frag lane l: B[k=(l>>4)*8+j][n=l&15] = Bt[n][k]; D lane l reg r: C[(l>>4)*4+r][l&15].
template<int K, bool RELU, typename OutT>
__launch_bounds__(256)
__global__ void gemm_bias_kernel(const __bf16* __restrict__ A, const __bf16* __restrict__ Bt,
                                 const float* __restrict__ bias, OutT* __restrict__ C,
                                 int M, int N) {
    constexpr int LDA = 40;  // 32 + 8 halves pad: row stride 80B (16B-aligned, bank-spread)
    __shared__ __align__(16) __bf16 la[64 * LDA];
    __shared__ __align__(16) __bf16 lb[64 * LDA];
    int tid  = threadIdx.x;
    int wave = tid >> 6, lane = tid & 63;
    int quad = lane >> 4, l15 = lane & 15;
    int wm = (wave >> 1) * 32, wn = (wave & 1) * 32;
    int tm = blockIdx.x * 64, tn = blockIdx.y * 64;

    v4f acc[2][2] = {};

    // staging: each thread loads one 16B chunk of A-tile and one of B-tile per k-step
    int srow = tid >> 2;               // 0..63
    int sseg = (tid & 3) * 8;          // halves within 32-wide k block
    long arow = tm + srow;
    if (arow >= M) arow = M - 1;       // clamp: garbage rows only affect unstored outputs
    const __bf16* ag = A  + (size_t)arow * K + sseg;
    const __bf16* bg = Bt + (size_t)(tn + srow) * K + sseg;  // N divisible by 64

    for (int k0 = 0; k0 < K; k0 += 32) {
        __syncthreads();
        uint4 av = *(const uint4*)(ag + k0);
        uint4 bv = *(const uint4*)(bg + k0);
        *(uint4*)&la[srow * LDA + sseg] = av;
        *(uint4*)&lb[srow * LDA + sseg] = bv;
        __syncthreads();

        v8bf af0 = *(const v8bf*)&la[(wm +      l15) * LDA + quad * 8];
        v8bf af1 = *(const v8bf*)&la[(wm + 16 + l15) * LDA + quad * 8];
        v8bf bf0 = *(const v8bf*)&lb[(wn +      l15) * LDA + quad * 8];
        v8bf bf1 = *(const v8bf*)&lb[(wn + 16 + l15) * LDA + quad * 8];

        acc[0][0] = __builtin_amdgcn_mfma_f32_16x16x32_bf16(af0, bf0, acc[0][0], 0, 0, 0);
        acc[0][1] = __builtin_amdgcn_mfma_f32_16x16x32_bf16(af0, bf1, acc[0][1], 0, 0, 0);
        acc[1][0] = __builtin_amdgcn_mfma_f32_16x16x32_bf16(af1, bf0, acc[1][0], 0, 0, 0);
        acc[1][1] = __builtin_amdgcn_mfma_f32_16x16x32_bf16(af1, bf1, acc[1][1], 0, 0, 0);
    }

#pragma unroll
    for (int mi = 0; mi < 2; mi++) {
#pragma unroll
        for (int r = 0; r < 4; r++) {
            int row = tm + wm + mi * 16 + quad * 4 + r;
            if (row < M) {
#pragma unroll
                for (int ni = 0; ni < 2; ni++) {
                    int col = tn + wn + ni * 16 + l15;
                    float v = acc[mi][ni][r] + bias[col];
                    if (RELU) v = fmaxf(v, 0.0f);
                    C[(size_t)row * N + col] = (OutT)v;
                }
            }
        }
    }
}

// ---------------- host ----------------
static inline size_t align256(size_t x) { return (x + 255) & ~(size_t)255; }

extern "C" void kernel_launch(void* const* d_in, const int* in_sizes, int n_in,
                              void* d_out, int out_size, void* d_ws, size_t ws_size,
                              hipStream_t stream) {
    const float* x   = (const float*)d_in[0];
    const int*   ei0 = (const int*)d_in[1];
    const int*   ei1 = (const int*)d_in[2];
    const int*   ei2 = (const int*)d_in[3];
    const float* W0  = (const float*)d_in[4];
    const float* b0  = (const float*)d_in[5];
    const float* W1  = (const float*)d_in[6];
    const float* b1  = (const float*)d_in[7];
    const float* W2  = (const float*)d_in[8];
    const float* b2  = (const float*)d_in[9];
    float* out = (float*)d_out;

    // ---- workspace carve-up (re-poisoned to 0xAA each call; we init what we read) ----
    char* ws = (char*)d_ws;
    size_t o = 0;
    auto alloc = [&](size_t bytes) { void* p = ws + o; o += align256(bytes); return p; };
    int*    deg    = (int*)   alloc((size_t)cN1 * 4);
    int*    cnt    = (int*)   alloc((size_t)cN1 * 4);
    int*    off    = (int*)   alloc((size_t)cN1 * 4);
    int*    cur    = (int*)   alloc((size_t)cN1 * 4);
    float*  dis    = (float*) alloc((size_t)cN1 * 4);
    int*    cursor = (int*)   alloc(256);
    int*    csr    = (int*)   alloc((size_t)cE0 * 4);
    __bf16* w0t    = (__bf16*)alloc((size_t)F_IN * F_HID * 2);
    __bf16* w1t    = (__bf16*)alloc((size_t)F_HID * F_HID * 2);
    __bf16* w2t    = (__bf16*)alloc((size_t)F_HID * F_HID * 2);
    __bf16* aggb   = (__bf16*)alloc((size_t)cN1 * F_HID * 2);  // max of all agg uses
    __bf16* h1     = (__bf16*)alloc((size_t)cN1 * F_HID * 2);
    __bf16* h2     = (__bf16*)alloc((size_t)cN2 * F_HID * 2);
    (void)ws_size; (void)n_in; (void)in_sizes; (void)out_size;

    // ---- weight conversion (tiny) ----
    wconv_kernel<<<(F_IN * F_HID + 255) / 256, 256, 0, stream>>>(W0, F_IN, F_HID, w0t);
    wconv_kernel<<<(F_HID * F_HID + 255) / 256, 256, 0, stream>>>(W1, F_HID, F_HID, w1t);
    wconv_kernel<<<(F_HID * F_HID + 255) / 256, 256, 0, stream>>>(W2, F_HID, F_HID, w2t);

    auto build_csr = [&](const int* ei, int E, int n_dst, float fill) {
        hipMemsetAsync(deg, 0, (size_t)n_dst * 4, stream);
        hipMemsetAsync(cnt, 0, (size_t)n_dst * 4, stream);
        hipMemsetAsync(cursor, 0, 4, stream);
        count_kernel<<<(E + 255) / 256, 256, 0, stream>>>(ei, ei + E, E, n_dst, deg, cnt);
        offsets_kernel<<<(n_dst + 255) / 256, 256, 0, stream>>>(deg, cnt, n_dst, fill,
                                                                dis, off, cur, cursor);
        scatter_kernel<<<(E + 255) / 256, 256, 0, stream>>>(ei, ei + E, E, n_dst, cur, csr);
    };

    // ---- layer 0: x[400000,128] -> h1[200000,256], fill=2, ReLU ----
    build_csr(ei0, cE0, cN1, 2.0f);
    agg_f32_kernel<<<cN1, 128, 0, stream>>>(x, dis, off, cnt, csr, 2.0f, aggb);
    gemm_bias_kernel<F_IN, true, __bf16><<<dim3((cN1 + 63) / 64, F_HID / 64), 256, 0, stream>>>(
        aggb, w0t, b0, h1, cN1, F_HID);

    // ---- layer 1: h1[200000,256] -> h2[100000,256], fill=2, ReLU ----
    build_csr(ei1, cE1, cN2, 2.0f);
    agg_bf16_kernel<<<cN2, 128, 0, stream>>>(h1, dis, off, cnt, csr, 2.0f, aggb);
    gemm_bias_kernel<F_HID, true, __bf16><<<dim3((cN2 + 63) / 64, F_HID / 64), 256, 0, stream>>>(
        aggb, w1t, b1, h2, cN2, F_HID);

    // ---- layer 2: h2[100000,256] -> out[50000,256], fill=1, no ReLU, fp32 out ----
    build_csr(ei2, cE2, cN3, 1.0f);
    agg_bf16_kernel<<<cN3, 128, 0, stream>>>(h2, dis, off, cnt, csr, 1.0f, aggb);
    gemm_bias_kernel<F_HID, false, float><<<dim3((cN3 + 63) / 64, F_HID / 64), 256, 0, stream>>>(
        aggb, w2t, b2, out, cN3, F_HID);
}

// Round 2
// 1201.780 us; speedup vs baseline: 1.1637x; 1.1637x over previous
//
#include <hip/hip_runtime.h>

typedef __bf16 v8bf __attribute__((ext_vector_type(8)));
typedef __bf16 v4bf __attribute__((ext_vector_type(4)));
typedef __bf16 v2bf __attribute__((ext_vector_type(2)));
typedef float  v4f  __attribute__((ext_vector_type(4)));

// ---- problem constants (from reference) ----
static constexpr int cN1 = 200000, cN2 = 100000, cN3 = 50000;
static constexpr int cE0 = 3200000, cE1 = 1600000, cE2 = 800000;
static constexpr int F_IN = 128, F_HID = 256;

// ---------------- x convert: fp32 -> bf16 (gather working set 205->102 MB, fits L3) ---------
__global__ void xconv_kernel(const float* __restrict__ x, __bf16* __restrict__ xb, int n4) {
    int i = blockIdx.x * blockDim.x + threadIdx.x;
    if (i >= n4) return;
    v4f v = *(const v4f*)(x + (size_t)i * 4);
    v4bf r;
    r.x = (__bf16)v.x; r.y = (__bf16)v.y; r.z = (__bf16)v.z; r.w = (__bf16)v.w;
    *(v4bf*)(xb + (size_t)i * 4) = r;
}

// ---------------- W convert: fp32 [K,N] -> bf16 transposed [N,K] ----------------
__global__ void wconv_kernel(const float* __restrict__ W, int K, int N,
                             __bf16* __restrict__ Wt) {
    int i = blockIdx.x * blockDim.x + threadIdx.x;
    if (i >= K * N) return;
    int k = i / N, n = i - k * N;
    Wt[(size_t)n * K + k] = (__bf16)W[i];
}

// ---------------- CSR build ----------------
// packed[c]: low 16 = degree (ALL edges, reference semantics), high 16 = contributing count
// (only edges with row < n_dst contribute: dis[row]=0 otherwise). Max deg ~50 << 65536.
__global__ void count_kernel(const int* __restrict__ rows, const int* __restrict__ cols,
                             int E, int n_dst, int* __restrict__ pk) {
    int e = blockIdx.x * blockDim.x + threadIdx.x;
    if (e >= E) return;
    int c = cols[e];
    int add = 1 + ((rows[e] < n_dst) ? (1 << 16) : 0);
    atomicAdd(&pk[c], add);
}

__global__ void offsets_kernel(const int* __restrict__ pk, int n_dst, float fill,
                               float* __restrict__ dis, int* __restrict__ off,
                               int* __restrict__ cur, int* __restrict__ cursor) {
    int c = blockIdx.x * blockDim.x + threadIdx.x;
    if (c >= n_dst) return;
    int p = pk[c];
    int deg = p & 0xffff, cnt = p >> 16;
    dis[c] = rsqrtf((float)deg + fill);      // deg+fill >= 1 always for c < n_dst
    int o = atomicAdd(cursor, cnt);          // CSR segment order irrelevant for a sum
    off[c] = o;
    cur[c] = o;
}

__global__ void scatter_kernel(const int* __restrict__ rows, const int* __restrict__ cols,
                               int E, int n_dst, int* __restrict__ cur, int* __restrict__ csr) {
    int e = blockIdx.x * blockDim.x + threadIdx.x;
    if (e >= E) return;
    int r = rows[e];
    if (r < n_dst) {
        int p = atomicAdd(&cur[cols[e]], 1);
        csr[p] = r;
    }
}

// ---------------- aggregation: one WAVE per target, readlane broadcast ----------------
// agg[c] = fill*dis[c]^2*src[c] + sum_e dis[row]*dis[c]*src[row]
// cur_end[c] == off[c] + cnt[c] after scatter_kernel (atomic cursor final value).
// Lanes batch-load 64 (index, coef) pairs, then inner loop broadcasts via v_readlane
// (uniform loop idx -> SGPR row base, saddr gather). Row loads across iterations are
// independent -> vmcnt pipelining instead of the round-1 serial 3-load chain per edge.
template<int F>
__launch_bounds__(256)
__global__ void agg_kernel(const __bf16* __restrict__ src, const float* __restrict__ dis,
                           const int* __restrict__ off, const int* __restrict__ cur_end,
                           const int* __restrict__ csr, float fill, int n_dst,
                           __bf16* __restrict__ out) {
    constexpr int VPL = F / 64;                 // bf16 elems per lane: 2 (F=128) / 4 (F=256)
    int wv = threadIdx.x >> 6, lane = threadIdx.x & 63;
    int c = blockIdx.x * 4 + wv;
    if (c >= n_dst) return;                     // uniform per wave

    float dc = dis[c];
    float self = fill * dc * dc;
    int loff = lane * VPL;
    const __bf16* selfp = src + (size_t)c * F + loff;
    float acc[VPL];
    if constexpr (VPL == 2) {
        v2bf w = *(const v2bf*)selfp;
        acc[0] = self * (float)w.x; acc[1] = self * (float)w.y;
    } else {
        v4bf w = *(const v4bf*)selfp;
        acc[0] = self * (float)w.x; acc[1] = self * (float)w.y;
        acc[2] = self * (float)w.z; acc[3] = self * (float)w.w;
    }

    int o = off[c];
    int n = cur_end[c] - o;                     // contributing-edge count
    for (int base = 0; base < n; base += 64) {
        int m = n - base; if (m > 64) m = 64;
        int r = 0; float cf = 0.0f;
        if (lane < m) {                          // one chained load pair per 64 edges
            r = csr[o + base + lane];
            cf = dis[r] * dc;
        }
        for (int i = 0; i < m; i++) {
            int r2 = __builtin_amdgcn_readlane(r, i);
            int cbits = __builtin_amdgcn_readlane(__builtin_bit_cast(int, cf), i);
            float c2 = __builtin_bit_cast(float, cbits);
            const __bf16* p = src + (size_t)r2 * F + loff;
            if constexpr (VPL == 2) {
                v2bf w = *(const v2bf*)p;
                acc[0] += c2 * (float)w.x; acc[1] += c2 * (float)w.y;
            } else {
                v4bf w = *(const v4bf*)p;
                acc[0] += c2 * (float)w.x; acc[1] += c2 * (float)w.y;
                acc[2] += c2 * (float)w.z; acc[3] += c2 * (float)w.w;
            }
        }
    }

    __bf16* op = out + (size_t)c * F + loff;
    if constexpr (VPL == 2) {
        v2bf res; res.x = (__bf16)acc[0]; res.y = (__bf16)acc[1];
        *(v2bf*)op = res;
    } else {
        v4bf res; res.x = (__bf16)acc[0]; res.y = (__bf16)acc[1];
        res.z = (__bf16)acc[2]; res.w = (__bf16)acc[3];
        *(v4bf*)op = res;
    }
}

// ---------------- GEMM: C[M,N] = A[M,K] @ B[K,N] + bias (opt ReLU) ----------------
// A bf16 row-major [M,K]; Bt bf16 = B transposed, row-major [N,K]. 64x64 tile,
// 4 waves each 32x32 via mfma_f32_16x16x32_bf16.
// Verified gfx950 layouts: A-frag lane l: A[m=l&15][k=(l>>4)*8+j];
// B-frag lane l: B[k=(l>>4)*8+j][n=l&15] = Bt[n][k]; D lane l reg r: C[(l>>4)*4+r][l&15].
template<int K, bool RELU, typename OutT>
__launch_bounds__(256)
__global__ void gemm_bias_kernel(const __bf16* __restrict__ A, const __bf16* __restrict__ Bt,
                                 const float* __restrict__ bias, OutT* __restrict__ C,
                                 int M, int N) {
    constexpr int LDA = 40;  // 32 + 8 halves pad: row stride 80B (16B-aligned, bank-spread)
    __shared__ __align__(16) __bf16 la[64 * LDA];
    __shared__ __align__(16) __bf16 lb[64 * LDA];
    int tid  = threadIdx.x;
    int wave = tid >> 6, lane = tid & 63;
    int quad = lane >> 4, l15 = lane & 15;
    int wm = (wave >> 1) * 32, wn = (wave & 1) * 32;
    int tm = blockIdx.x * 64, tn = blockIdx.y * 64;

    v4f acc[2][2] = {};

    int srow = tid >> 2;               // 0..63
    int sseg = (tid & 3) * 8;          // halves within 32-wide k block
    long arow = tm + srow;
    if (arow >= M) arow = M - 1;       // clamp: garbage rows only affect unstored outputs
    const __bf16* ag = A  + (size_t)arow * K + sseg;
    const __bf16* bg = Bt + (size_t)(tn + srow) * K + sseg;  // N divisible by 64

    for (int k0 = 0; k0 < K; k0 += 32) {
        __syncthreads();
        uint4 av = *(const uint4*)(ag + k0);
        uint4 bv = *(const uint4*)(bg + k0);
        *(uint4*)&la[srow * LDA + sseg] = av;
        *(uint4*)&lb[srow * LDA + sseg] = bv;
        __syncthreads();

        v8bf af0 = *(const v8bf*)&la[(wm +      l15) * LDA + quad * 8];
        v8bf af1 = *(const v8bf*)&la[(wm + 16 + l15) * LDA + quad * 8];
        v8bf bf0 = *(const v8bf*)&lb[(wn +      l15) * LDA + quad * 8];
        v8bf bf1 = *(const v8bf*)&lb[(wn + 16 + l15) * LDA + quad * 8];

        acc[0][0] = __builtin_amdgcn_mfma_f32_16x16x32_bf16(af0, bf0, acc[0][0], 0, 0, 0);
        acc[0][1] = __builtin_amdgcn_mfma_f32_16x16x32_bf16(af0, bf1, acc[0][1], 0, 0, 0);
        acc[1][0] = __builtin_amdgcn_mfma_f32_16x16x32_bf16(af1, bf0, acc[1][0], 0, 0, 0);
        acc[1][1] = __builtin_amdgcn_mfma_f32_16x16x32_bf16(af1, bf1, acc[1][1], 0, 0, 0);
    }

#pragma unroll
    for (int mi = 0; mi < 2; mi++) {
#pragma unroll
        for (int r = 0; r < 4; r++) {
            int row = tm + wm + mi * 16 + quad * 4 + r;
            if (row < M) {
#pragma unroll
                for (int ni = 0; ni < 2; ni++) {
                    int col = tn + wn + ni * 16 + l15;
                    float v = acc[mi][ni][r] + bias[col];
                    if (RELU) v = fmaxf(v, 0.0f);
                    C[(size_t)row * N + col] = (OutT)v;
                }
            }
        }
    }
}

// ---------------- host ----------------
static inline size_t align256(size_t x) { return (x + 255) & ~(size_t)255; }

extern "C" void kernel_launch(void* const* d_in, const int* in_sizes, int n_in,
                              void* d_out, int out_size, void* d_ws, size_t ws_size,
                              hipStream_t stream) {
    const float* x   = (const float*)d_in[0];
    const int*   ei0 = (const int*)d_in[1];
    const int*   ei1 = (const int*)d_in[2];
    const int*   ei2 = (const int*)d_in[3];
    const float* W0  = (const float*)d_in[4];
    const float* b0  = (const float*)d_in[5];
    const float* W1  = (const float*)d_in[6];
    const float* b1  = (const float*)d_in[7];
    const float* W2  = (const float*)d_in[8];
    const float* b2  = (const float*)d_in[9];
    float* out = (float*)d_out;

    // ---- workspace carve-up (re-poisoned to 0xAA each call; we init what we read) ----
    char* ws = (char*)d_ws;
    size_t o = 0;
    auto alloc = [&](size_t bytes) { void* p = ws + o; o += align256(bytes); return p; };
    int*    pk     = (int*)   alloc((size_t)cN1 * 4);   // packed deg|cnt
    int*    off    = (int*)   alloc((size_t)cN1 * 4);
    int*    cur    = (int*)   alloc((size_t)cN1 * 4);
    float*  dis    = (float*) alloc((size_t)cN1 * 4);
    int*    cursor = (int*)   alloc(256);
    int*    csr    = (int*)   alloc((size_t)cE0 * 4);
    __bf16* w0t    = (__bf16*)alloc((size_t)F_IN * F_HID * 2);
    __bf16* w1t    = (__bf16*)alloc((size_t)F_HID * F_HID * 2);
    __bf16* w2t    = (__bf16*)alloc((size_t)F_HID * F_HID * 2);
    __bf16* aggb   = (__bf16*)alloc((size_t)cN1 * F_IN * 2);   // 51.2 MB, max agg size
    __bf16* h1     = (__bf16*)alloc((size_t)cN1 * F_HID * 2);  // 102.4 MB
    // union: xb (400K x 128 bf16 = 102.4 MB, dead after L0 agg) overlaps h2
    // (100K x 256 bf16 = 51.2 MB, first written at L1 GEMM, after xb is dead)
    __bf16* xb     = (__bf16*)alloc((size_t)400000 * F_IN * 2);
    __bf16* h2     = xb;
    (void)ws_size; (void)n_in; (void)in_sizes; (void)out_size;

    // ---- conversions ----
    {
        int n4 = 400000 * F_IN / 4;
        xconv_kernel<<<(n4 + 255) / 256, 256, 0, stream>>>(x, xb, n4);
    }
    wconv_kernel<<<(F_IN * F_HID + 255) / 256, 256, 0, stream>>>(W0, F_IN, F_HID, w0t);
    wconv_kernel<<<(F_HID * F_HID + 255) / 256, 256, 0, stream>>>(W1, F_HID, F_HID, w1t);
    wconv_kernel<<<(F_HID * F_HID + 255) / 256, 256, 0, stream>>>(W2, F_HID, F_HID, w2t);

    auto build_csr = [&](const int* ei, int E, int n_dst, float fill) {
        hipMemsetAsync(pk, 0, (size_t)n_dst * 4, stream);
        hipMemsetAsync(cursor, 0, 4, stream);
        count_kernel<<<(E + 255) / 256, 256, 0, stream>>>(ei, ei + E, E, n_dst, pk);
        offsets_kernel<<<(n_dst + 255) / 256, 256, 0, stream>>>(pk, n_dst, fill,
                                                                dis, off, cur, cursor);
        scatter_kernel<<<(E + 255) / 256, 256, 0, stream>>>(ei, ei + E, E, n_dst, cur, csr);
    };

    // ---- layer 0: x[400000,128] -> h1[200000,256], fill=2, ReLU ----
    build_csr(ei0, cE0, cN1, 2.0f);
    agg_kernel<F_IN><<<(cN1 + 3) / 4, 256, 0, stream>>>(xb, dis, off, cur, csr, 2.0f, cN1, aggb);
    gemm_bias_kernel<F_IN, true, __bf16><<<dim3((cN1 + 63) / 64, F_HID / 64), 256, 0, stream>>>(
        aggb, w0t, b0, h1, cN1, F_HID);

    // ---- layer 1: h1[200000,256] -> h2[100000,256], fill=2, ReLU ----
    build_csr(ei1, cE1, cN2, 2.0f);
    agg_kernel<F_HID><<<(cN2 + 3) / 4, 256, 0, stream>>>(h1, dis, off, cur, csr, 2.0f, cN2, aggb);
    gemm_bias_kernel<F_HID, true, __bf16><<<dim3((cN2 + 63) / 64, F_HID / 64), 256, 0, stream>>>(
        aggb, w1t, b1, h2, cN2, F_HID);

    // ---- layer 2: h2[100000,256] -> out[50000,256], fill=1, no ReLU, fp32 out ----
    build_csr(ei2, cE2, cN3, 1.0f);
    agg_kernel<F_HID><<<(cN3 + 3) / 4, 256, 0, stream>>>(h2, dis, off, cur, csr, 1.0f, cN3, aggb);
    gemm_bias_kernel<F_HID, false, float><<<dim3((cN3 + 63) / 64, F_HID / 64), 256, 0, stream>>>(
        aggb, w2t, b2, out, cN3, F_HID);
}

// Round 3
// 1064.174 us; speedup vs baseline: 1.3141x; 1.1293x over previous
//
#include <hip/hip_runtime.h>

typedef __bf16 v8bf __attribute__((ext_vector_type(8)));
typedef __bf16 v4bf __attribute__((ext_vector_type(4)));
typedef float  v4f  __attribute__((ext_vector_type(4)));

// ---- problem constants (from reference) ----
static constexpr int cN1 = 200000, cN2 = 100000, cN3 = 50000;
static constexpr int cE0 = 3200000, cE1 = 1600000, cE2 = 800000;
static constexpr int F_IN = 128, F_HID = 256;

// ---------------- x convert: fp32 -> bf16 (gather working set 205->102 MB, fits L3) ---------
__global__ void xconv_kernel(const float* __restrict__ x, __bf16* __restrict__ xb, int n4) {
    int i = blockIdx.x * blockDim.x + threadIdx.x;
    if (i >= n4) return;
    v4f v = *(const v4f*)(x + (size_t)i * 4);
    v4bf r;
    r.x = (__bf16)v.x; r.y = (__bf16)v.y; r.z = (__bf16)v.z; r.w = (__bf16)v.w;
    *(v4bf*)(xb + (size_t)i * 4) = r;
}

// ---------------- W convert: fp32 [K,N] -> bf16 transposed [N,K] ----------------
__global__ void wconv_kernel(const float* __restrict__ W, int K, int N,
                             __bf16* __restrict__ Wt) {
    int i = blockIdx.x * blockDim.x + threadIdx.x;
    if (i >= K * N) return;
    int k = i / N, n = i - k * N;
    Wt[(size_t)n * K + k] = (__bf16)W[i];
}

// ---------------- CSR build ----------------
// packed[c]: low 16 = degree (ALL edges, reference semantics), high 16 = contributing count
// (only edges with row < n_dst contribute: dis[row]=0 otherwise). Max deg ~60 << 65536.
__global__ void count_kernel(const int* __restrict__ rows, const int* __restrict__ cols,
                             int E, int n_dst, int* __restrict__ pk) {
    int e = blockIdx.x * blockDim.x + threadIdx.x;
    if (e >= E) return;
    int c = cols[e];
    int add = 1 + ((rows[e] < n_dst) ? (1 << 16) : 0);
    atomicAdd(&pk[c], add);
}

// hdr[c] = {off, cnt, bits(selfw), 0};  selfw = fill * dis[c]^2 = fill/(deg+fill)
__global__ void offsets_kernel(const int* __restrict__ pk, int n_dst, float fill,
                               float* __restrict__ dis, int4* __restrict__ hdr,
                               int* __restrict__ cur, int* __restrict__ cursor) {
    int c = blockIdx.x * blockDim.x + threadIdx.x;
    if (c >= n_dst) return;
    int p = pk[c];
    int deg = p & 0xffff, cnt = p >> 16;
    float d = rsqrtf((float)deg + fill);     // deg+fill >= 1 always for c < n_dst
    dis[c] = d;
    float selfw = fill * d * d;
    int o = atomicAdd(cursor, cnt);          // CSR segment order irrelevant for a sum
    hdr[c] = make_int4(o, cnt, __builtin_bit_cast(int, selfw), 0);
    cur[c] = o;
}

// csr2[p] = {row, bits(dis[row]*dis[col])} -- coef precomputed so the agg hot loop
// has a 2-deep chain (idx -> row) instead of 3-deep (idx -> dis -> row).
__global__ void scatter_kernel(const int* __restrict__ rows, const int* __restrict__ cols,
                               int E, int n_dst, const float* __restrict__ dis,
                               int* __restrict__ cur, int2* __restrict__ csr2) {
    int e = blockIdx.x * blockDim.x + threadIdx.x;
    if (e >= E) return;
    int r = rows[e];
    if (r < n_dst) {
        int c = cols[e];
        int p = atomicAdd(&cur[c], 1);
        float coef = dis[r] * dis[c];
        csr2[p] = make_int2(r, __builtin_bit_cast(int, coef));
    }
}

// ---------------- aggregation v3: one 16/32-lane GROUP per target ----------------
// agg[c] = selfw*src[c] + sum_e coef_e * src[row_e]
// Lane t of a group covers features [8t, 8t+8) via one 16 B v8bf load -> a full row is
// one coalesced load instruction per group. Unroll-2: two row loads in flight per group,
// next pair's (row,coef) prefetched while current rows load. ~128 groups/CU of TLP.
template<int F>
__launch_bounds__(256)
__global__ void agg_kernel(const __bf16* __restrict__ src, const int4* __restrict__ hdr,
                           const int2* __restrict__ csr2, int n_dst,
                           __bf16* __restrict__ out) {
    constexpr int T = F / 8;            // lanes per target row (16 B each): 16 or 32
    constexpr int TPB = 256 / T;        // targets per block: 16 or 8
    int tid = threadIdx.x;
    int grp = tid / T;
    int t   = tid % T;
    int c = blockIdx.x * TPB + grp;
    if (c >= n_dst) return;

    int4 h = hdr[c];                    // broadcast within group
    int o = h.x, n = h.y;
    float selfw = __builtin_bit_cast(float, h.z);

    v8bf sv = *(const v8bf*)(src + (size_t)c * F + t * 8);
    float acc[8];
#pragma unroll
    for (int j = 0; j < 8; j++) acc[j] = selfw * (float)sv[j];

    const int2* ep = csr2 + o;
    int2 ea, eb;
    if (n > 0) ea = ep[0];
    if (n > 1) eb = ep[1];
    int i = 0;
    for (; i + 2 <= n; i += 2) {
        int ra = ea.x; float ca = __builtin_bit_cast(float, ea.y);
        int rb = eb.x; float cb = __builtin_bit_cast(float, eb.y);
        v8bf wa = *(const v8bf*)(src + (size_t)(unsigned)(ra * F) + t * 8);
        v8bf wb = *(const v8bf*)(src + (size_t)(unsigned)(rb * F) + t * 8);
        if (i + 2 < n) ea = ep[i + 2];  // prefetch while rows are in flight
        if (i + 3 < n) eb = ep[i + 3];
#pragma unroll
        for (int j = 0; j < 8; j++) acc[j] += ca * (float)wa[j];
#pragma unroll
        for (int j = 0; j < 8; j++) acc[j] += cb * (float)wb[j];
    }
    if (i < n) {
        int ra = ea.x; float ca = __builtin_bit_cast(float, ea.y);
        v8bf wa = *(const v8bf*)(src + (size_t)(unsigned)(ra * F) + t * 8);
#pragma unroll
        for (int j = 0; j < 8; j++) acc[j] += ca * (float)wa[j];
    }

    v8bf res;
#pragma unroll
    for (int j = 0; j < 8; j++) res[j] = (__bf16)acc[j];
    *(v8bf*)(out + (size_t)c * F + t * 8) = res;
}

// ---------------- GEMM: C[M,N] = A[M,K] @ B[K,N] + bias (opt ReLU) ----------------
// A bf16 row-major [M,K]; Bt bf16 = B transposed, row-major [N,K]. 64x64 tile,
// 4 waves each 32x32 via mfma_f32_16x16x32_bf16.
// Verified gfx950 layouts: A-frag lane l: A[m=l&15][k=(l>>4)*8+j];
// B-frag lane l: B[k=(l>>4)*8+j][n=l&15] = Bt[n][k]; D lane l reg r: C[(l>>4)*4+r][l&15].
template<int K, bool RELU, typename OutT>
__launch_bounds__(256)
__global__ void gemm_bias_kernel(const __bf16* __restrict__ A, const __bf16* __restrict__ Bt,
                                 const float* __restrict__ bias, OutT* __restrict__ C,
                                 int M, int N) {
    constexpr int LDA = 40;  // 32 + 8 halves pad: row stride 80B (16B-aligned, bank-spread)
    __shared__ __align__(16) __bf16 la[64 * LDA];
    __shared__ __align__(16) __bf16 lb[64 * LDA];
    int tid  = threadIdx.x;
    int wave = tid >> 6, lane = tid & 63;
    int quad = lane >> 4, l15 = lane & 15;
    int wm = (wave >> 1) * 32, wn = (wave & 1) * 32;
    int tm = blockIdx.x * 64, tn = blockIdx.y * 64;

    v4f acc[2][2] = {};

    int srow = tid >> 2;               // 0..63
    int sseg = (tid & 3) * 8;          // halves within 32-wide k block
    long arow = tm + srow;
    if (arow >= M) arow = M - 1;       // clamp: garbage rows only affect unstored outputs
    const __bf16* ag = A  + (size_t)arow * K + sseg;
    const __bf16* bg = Bt + (size_t)(tn + srow) * K + sseg;  // N divisible by 64

    for (int k0 = 0; k0 < K; k0 += 32) {
        __syncthreads();
        uint4 av = *(const uint4*)(ag + k0);
        uint4 bv = *(const uint4*)(bg + k0);
        *(uint4*)&la[srow * LDA + sseg] = av;
        *(uint4*)&lb[srow * LDA + sseg] = bv;
        __syncthreads();

        v8bf af0 = *(const v8bf*)&la[(wm +      l15) * LDA + quad * 8];
        v8bf af1 = *(const v8bf*)&la[(wm + 16 + l15) * LDA + quad * 8];
        v8bf bf0 = *(const v8bf*)&lb[(wn +      l15) * LDA + quad * 8];
        v8bf bf1 = *(const v8bf*)&lb[(wn + 16 + l15) * LDA + quad * 8];

        acc[0][0] = __builtin_amdgcn_mfma_f32_16x16x32_bf16(af0, bf0, acc[0][0], 0, 0, 0);
        acc[0][1] = __builtin_amdgcn_mfma_f32_16x16x32_bf16(af0, bf1, acc[0][1], 0, 0, 0);
        acc[1][0] = __builtin_amdgcn_mfma_f32_16x16x32_bf16(af1, bf0, acc[1][0], 0, 0, 0);
        acc[1][1] = __builtin_amdgcn_mfma_f32_16x16x32_bf16(af1, bf1, acc[1][1], 0, 0, 0);
    }

#pragma unroll
    for (int mi = 0; mi < 2; mi++) {
#pragma unroll
        for (int r = 0; r < 4; r++) {
            int row = tm + wm + mi * 16 + quad * 4 + r;
            if (row < M) {
#pragma unroll
                for (int ni = 0; ni < 2; ni++) {
                    int col = tn + wn + ni * 16 + l15;
                    float v = acc[mi][ni][r] + bias[col];
                    if (RELU) v = fmaxf(v, 0.0f);
                    C[(size_t)row * N + col] = (OutT)v;
                }
            }
        }
    }
}

// ---------------- host ----------------
static inline size_t align256(size_t x) { return (x + 255) & ~(size_t)255; }

extern "C" void kernel_launch(void* const* d_in, const int* in_sizes, int n_in,
                              void* d_out, int out_size, void* d_ws, size_t ws_size,
                              hipStream_t stream) {
    const float* x   = (const float*)d_in[0];
    const int*   ei0 = (const int*)d_in[1];
    const int*   ei1 = (const int*)d_in[2];
    const int*   ei2 = (const int*)d_in[3];
    const float* W0  = (const float*)d_in[4];
    const float* b0  = (const float*)d_in[5];
    const float* W1  = (const float*)d_in[6];
    const float* b1  = (const float*)d_in[7];
    const float* W2  = (const float*)d_in[8];
    const float* b2  = (const float*)d_in[9];
    float* out = (float*)d_out;

    // ---- workspace carve-up (re-poisoned to 0xAA each call; we init what we read) ----
    char* ws = (char*)d_ws;
    size_t o = 0;
    auto alloc = [&](size_t bytes) { void* p = ws + o; o += align256(bytes); return p; };
    int*    pk     = (int*)   alloc((size_t)cN1 * 4);    // packed deg|cnt
    int4*   hdr    = (int4*)  alloc((size_t)cN1 * 16);   // {off, cnt, selfw, 0}
    int*    cur    = (int*)   alloc((size_t)cN1 * 4);
    float*  dis    = (float*) alloc((size_t)cN1 * 4);
    int*    cursor = (int*)   alloc(256);
    int2*   csr2   = (int2*)  alloc((size_t)cE0 * 8);    // {row, coef} worst-case all edges
    __bf16* w0t    = (__bf16*)alloc((size_t)F_IN * F_HID * 2);
    __bf16* w1t    = (__bf16*)alloc((size_t)F_HID * F_HID * 2);
    __bf16* w2t    = (__bf16*)alloc((size_t)F_HID * F_HID * 2);
    __bf16* aggb   = (__bf16*)alloc((size_t)cN1 * F_IN * 2);   // 51.2 MB, max agg size
    __bf16* h1     = (__bf16*)alloc((size_t)cN1 * F_HID * 2);  // 102.4 MB
    // union: xb (400K x 128 bf16 = 102.4 MB, dead after L0 agg) overlaps h2
    // (100K x 256 bf16 = 51.2 MB, first written at L1 GEMM, after xb is dead)
    __bf16* xb     = (__bf16*)alloc((size_t)400000 * F_IN * 2);
    __bf16* h2     = xb;
    (void)ws_size; (void)n_in; (void)in_sizes; (void)out_size;

    // ---- conversions ----
    {
        int n4 = 400000 * F_IN / 4;
        xconv_kernel<<<(n4 + 255) / 256, 256, 0, stream>>>(x, xb, n4);
    }
    wconv_kernel<<<(F_IN * F_HID + 255) / 256, 256, 0, stream>>>(W0, F_IN, F_HID, w0t);
    wconv_kernel<<<(F_HID * F_HID + 255) / 256, 256, 0, stream>>>(W1, F_HID, F_HID, w1t);
    wconv_kernel<<<(F_HID * F_HID + 255) / 256, 256, 0, stream>>>(W2, F_HID, F_HID, w2t);

    auto build_csr = [&](const int* ei, int E, int n_dst, float fill) {
        hipMemsetAsync(pk, 0, (size_t)n_dst * 4, stream);
        hipMemsetAsync(cursor, 0, 4, stream);
        count_kernel<<<(E + 255) / 256, 256, 0, stream>>>(ei, ei + E, E, n_dst, pk);
        offsets_kernel<<<(n_dst + 255) / 256, 256, 0, stream>>>(pk, n_dst, fill,
                                                                dis, hdr, cur, cursor);
        scatter_kernel<<<(E + 255) / 256, 256, 0, stream>>>(ei, ei + E, E, n_dst,
                                                            dis, cur, csr2);
    };

    // ---- layer 0: x[400000,128] -> h1[200000,256], fill=2, ReLU ----
    build_csr(ei0, cE0, cN1, 2.0f);
    agg_kernel<F_IN><<<(cN1 + 15) / 16, 256, 0, stream>>>(xb, hdr, csr2, cN1, aggb);
    gemm_bias_kernel<F_IN, true, __bf16><<<dim3((cN1 + 63) / 64, F_HID / 64), 256, 0, stream>>>(
        aggb, w0t, b0, h1, cN1, F_HID);

    // ---- layer 1: h1[200000,256] -> h2[100000,256], fill=2, ReLU ----
    build_csr(ei1, cE1, cN2, 2.0f);
    agg_kernel<F_HID><<<(cN2 + 7) / 8, 256, 0, stream>>>(h1, hdr, csr2, cN2, aggb);
    gemm_bias_kernel<F_HID, true, __bf16><<<dim3((cN2 + 63) / 64, F_HID / 64), 256, 0, stream>>>(
        aggb, w1t, b1, h2, cN2, F_HID);

    // ---- layer 2: h2[100000,256] -> out[50000,256], fill=1, no ReLU, fp32 out ----
    build_csr(ei2, cE2, cN3, 1.0f);
    agg_kernel<F_HID><<<(cN3 + 7) / 8, 256, 0, stream>>>(h2, hdr, csr2, cN3, aggb);
    gemm_bias_kernel<F_HID, false, float><<<dim3((cN3 + 63) / 64, F_HID / 64), 256, 0, stream>>>(
        aggb, w2t, b2, out, cN3, F_HID);
}